// Round 9
// baseline (243.510 us; speedup 1.0000x reference)
//
#include <hip/hip_runtime.h>

// Fused attention prefill, bf16 MFMA pipeline.
// ws layout (ushort units, 1M = 1024*1024):
//   xb 0..4M | wqkvb 4M..10M | wob 10M..14M | qkvb 14M..20M | qb 20M..24M
//   kb 24M..25M | vt 25M..26M | yb 26M..30M   => 60 MB total.
// kb/vt layout: [kvh][tile(32)][512 chunks][8 ushort]; chunk (r,ch) of the
// 64x64 tile lives at linear pos r*8 + (ch ^ (r&7))  (bank-swizzle).
// kb rows r = keys (natural); vt rows r = dims, columns = sigma-permuted key
// positions: pos p holds key u=(p&3)*16+(p>>2), matching attn's P store.

typedef __attribute__((ext_vector_type(8))) __bf16 bf16x8;
typedef __attribute__((ext_vector_type(4))) float f32x4;

#define S_LEN 2048
#define DIMN  2048
#define NH    32
#define NKV   8
#define HD    64
#define QKVF  3072

__device__ __forceinline__ ushort f2bf(float f) {
  union { float f; unsigned u; } v; v.f = f;
  unsigned r = v.u + 0x7fffu + ((v.u >> 16) & 1u);
  return (ushort)(r >> 16);
}
__device__ __forceinline__ unsigned pack_bf2_rz(float a, float b) {
  union { float f; unsigned u; } va, vb; va.f = a; vb.f = b;
  return (va.u >> 16) | (vb.u & 0xffff0000u);
}
__device__ __forceinline__ float bf2f(ushort u) {
  union { unsigned u; float f; } v; v.u = ((unsigned)u) << 16;
  return v.f;
}
__device__ __forceinline__ void gld_lds16(const void* g, void* l) {
  __builtin_amdgcn_global_load_lds(
      (const __attribute__((address_space(1))) unsigned int*)g,
      (__attribute__((address_space(3))) unsigned int*)l, 16, 0, 0);
}

// ---------------- f32 -> bf16 conversion (x, [wq;wk;wv], wo) ----------------
__global__ __launch_bounds__(256) void convert_all(
    const float* __restrict__ x, const float* __restrict__ wq,
    const float* __restrict__ wk, const float* __restrict__ wv,
    const float* __restrict__ wo, ushort* __restrict__ xb,
    ushort* __restrict__ wqkvb, ushort* __restrict__ wob) {
  const size_t NX = 4u * 1024 * 1024;
  const size_t NK = 1024 * 1024;
  size_t idx = ((size_t)blockIdx.x * 256 + threadIdx.x) * 4;
  const float* src; ushort* dst;
  if (idx < NX)                { src = x  + idx;                  dst = xb + idx; }
  else if (idx < 2 * NX)       { src = wq + (idx - NX);           dst = wqkvb + (idx - NX); }
  else if (idx < 2 * NX + NK)  { src = wk + (idx - 2 * NX);       dst = wqkvb + NX + (idx - 2 * NX); }
  else if (idx < 2 * NX + 2*NK){ src = wv + (idx - 2 * NX - NK);  dst = wqkvb + NX + NK + (idx - 2 * NX - NK); }
  else                         { src = wo + (idx - 2 * NX - 2*NK);dst = wob + (idx - 2 * NX - 2 * NK); }
  float4 v = *(const float4*)src;
  ushort4 o; o.x = f2bf(v.x); o.y = f2bf(v.y); o.z = f2bf(v.z); o.w = f2bf(v.w);
  *(ushort4*)dst = o;
}

// ---------------- GEMM: dbuf LDS + XOR bank swizzle, BN=128 or 192 ----------
// BN=192 (qkv): grid 16x16=256 blocks, perfectly balanced on 256 CUs;
// LDS = 2*(128+192)*64*2 = 80 KB -> exactly 2 blocks/CU. BN=128 (wo): as R8.
// Chunk (row,ch) stored at physical ch^(row&7); staging permutes the GLOBAL
// source chunk per lane (coalescing unchanged); fragment reads use
// chunk=(c*4+quad)^(col&7) -> conflict-free (verified: 9.4M -> 0 in R8).
template <int OUT_BF16, int BN>
__global__ __launch_bounds__(256) void gemm_bt(
    const ushort* __restrict__ A, const ushort* __restrict__ B,
    void* __restrict__ Cv, int M, int N, int K) {
  constexpr int JB = BN / 32;       // j-blocks per wave (4 or 6)
  __shared__ __align__(16) ushort As[2][128 * 64];
  __shared__ __align__(16) ushort Bs[2][BN * 64];
  const int n0 = blockIdx.x * BN, m0 = blockIdx.y * 128;
  const int t = threadIdx.x;
  const int lane = t & 63, wave = t >> 6;
  const int wm = (wave >> 1) * 64, wn = (wave & 1) * (BN / 2);
  const int col = lane & 15, quad = lane >> 4;
  const int sw = col & 7;                     // fragment-read swizzle key
  const int lrow = lane >> 3;
  const int scol = ((lane & 7) ^ lrow) * 8;   // staged-source swizzle
  f32x4 acc[4][JB] = {};

  auto stage = [&](int b, int kk) {
#pragma unroll
    for (int c = 0; c < 4; ++c) {
      int row = wave * 32 + c * 8;
      gld_lds16(&A[(size_t)(m0 + row + lrow) * K + kk + scol], &As[b][row * 64]);
    }
#pragma unroll
    for (int c = 0; c < BN / 32; ++c) {
      int row = wave * (BN / 4) + c * 8;
      gld_lds16(&B[(size_t)(n0 + row + lrow) * K + kk + scol], &Bs[b][row * 64]);
    }
  };

  stage(0, 0);
  __syncthreads();
  for (int kk = 0; kk < K; kk += 64) {
    const int b = (kk >> 6) & 1;
    if (kk + 64 < K) stage(b ^ 1, kk + 64);
#pragma unroll
    for (int c = 0; c < 2; ++c) {
      const int chs = ((c * 4 + quad) ^ sw) * 8;
      bf16x8 af[4], bfr[JB];
#pragma unroll
      for (int i = 0; i < 4; ++i)
        af[i] = *(const bf16x8*)&As[b][(wm + i * 16 + col) * 64 + chs];
#pragma unroll
      for (int j = 0; j < JB; ++j)
        bfr[j] = *(const bf16x8*)&Bs[b][(wn + j * 16 + col) * 64 + chs];
#pragma unroll
      for (int i = 0; i < 4; ++i)
#pragma unroll
        for (int j = 0; j < JB; ++j)
          acc[i][j] = __builtin_amdgcn_mfma_f32_16x16x32_bf16(af[i], bfr[j], acc[i][j], 0, 0, 0);
    }
    __syncthreads();
  }
#pragma unroll
  for (int i = 0; i < 4; ++i)
#pragma unroll
    for (int r = 0; r < 4; ++r) {
      int m = m0 + wm + i * 16 + quad * 4 + r;
      if (OUT_BF16) {
        ushort* C = (ushort*)Cv;
#pragma unroll
        for (int j = 0; j < JB; ++j)
          C[(size_t)m * N + n0 + wn + j * 16 + col] = f2bf(acc[i][j][r]);
      } else {
        float* C = (float*)Cv;
#pragma unroll
        for (int j = 0; j < JB; ++j)
          C[(size_t)m * N + n0 + wn + j * 16 + col] = acc[i][j][r];
      }
    }
}

// ---------------- RoPE + layout ---------------------------------------------
__global__ __launch_bounds__(256) void rope_layout(
    const ushort* __restrict__ qkv, const float* __restrict__ fc,
    const float* __restrict__ fs, ushort* __restrict__ qb,
    ushort* __restrict__ kb, ushort* __restrict__ vt) {
  __shared__ ushort T[64][72];
  const int hh = blockIdx.x;
  const int s0 = blockIdx.y * 256;
  const int t = threadIdx.x;
  if (hh < 32) {
    ushort* dst = qb + (size_t)hh * S_LEN * 64;
    const float qs = 0.18033688011112042f;  // (1/8)*log2(e)
    const int sr = t >> 4, dc = (t & 15) * 4, i0 = (t & 15) * 2;
#pragma unroll 4
    for (int pass = 0; pass < 16; ++pass) {
      int s = s0 + pass * 16 + sr;
      ushort4 vv = *(const ushort4*)&qkv[(size_t)s * QKVF + hh * 64 + dc];
      float2 cc = *(const float2*)&fc[s * 32 + i0];
      float2 ss = *(const float2*)&fs[s * 32 + i0];
      float xr0 = bf2f(vv.x), xi0 = bf2f(vv.y), xr1 = bf2f(vv.z), xi1 = bf2f(vv.w);
      ushort4 ov;
      ov.x = f2bf((xr0 * cc.x - xi0 * ss.x) * qs); ov.y = f2bf((xr0 * ss.x + xi0 * cc.x) * qs);
      ov.z = f2bf((xr1 * cc.y - xi1 * ss.y) * qs); ov.w = f2bf((xr1 * ss.y + xi1 * cc.y) * qs);
      *(ushort4*)&dst[(size_t)s * 64 + dc] = ov;
    }
  } else if (hh < 40) {
    const int kh2 = hh - 32;
    const int sr8 = t >> 3;
    const int ch = t & 7;
#pragma unroll 2
    for (int pass = 0; pass < 8; ++pass) {
      int s = s0 + pass * 32 + sr8;
      ushort in[8], out[8];
      *(int4*)&in[0] = *(const int4*)&qkv[(size_t)s * QKVF + 2048 + kh2 * 64 + ch * 8];
      float4 cc = *(const float4*)&fc[s * 32 + ch * 4];
      float4 ss4 = *(const float4*)&fs[s * 32 + ch * 4];
      const float* cp = &cc.x; const float* sp = &ss4.x;
#pragma unroll
      for (int i = 0; i < 4; ++i) {
        float xr = bf2f(in[2 * i]), xi = bf2f(in[2 * i + 1]);
        out[2 * i]     = f2bf(xr * cp[i] - xi * sp[i]);
        out[2 * i + 1] = f2bf(xr * sp[i] + xi * cp[i]);
      }
      int r = s & 63, tile = s >> 6;
      size_t pos = ((size_t)(kh2 * 32 + tile)) * 4096 + (r * 8 + (ch ^ (r & 7))) * 8;
      *(int4*)&kb[pos] = *(const int4*)&out[0];
    }
  } else {
    const int vh = hh - 40;
    for (int sub = 0; sub < 4; ++sub) {
      int sb = s0 + sub * 64;
      int sr = t >> 2, dc = (t & 3) * 16;
      ushort tmp[16];
      *(int4*)&tmp[0] = *(const int4*)&qkv[(size_t)(sb + sr) * QKVF + 2560 + vh * 64 + dc];
      *(int4*)&tmp[8] = *(const int4*)&qkv[(size_t)(sb + sr) * QKVF + 2560 + vh * 64 + dc + 8];
      __syncthreads();
      const int pcol = ((sr & 15) << 2) | (sr >> 4);  // sigma: key sr -> position
#pragma unroll
      for (int k = 0; k < 16; ++k) T[dc + k][pcol] = tmp[k];
      __syncthreads();
      int d = t >> 2;
      int ch0 = (t & 3) * 2, ch1 = ch0 + 1;
      int tile = sb >> 6;
      size_t base = ((size_t)(vh * 32 + tile)) * 4096;
      *(int4*)&vt[base + (d * 8 + (ch0 ^ (d & 7))) * 8] = *(const int4*)&T[d][ch0 * 8];
      *(int4*)&vt[base + (d * 8 + (ch1 ^ (d & 7))) * 8] = *(const int4*)&T[d][ch1 * 8];
    }
  }
}

// ---------------- Flash attention v7: LDS-shared KV, 4 GQA heads per block --
__global__ __launch_bounds__(256, 2) void attn(
    const ushort* __restrict__ qbg, const ushort* __restrict__ kbg,
    const ushort* __restrict__ vtg, ushort* __restrict__ yb) {
  __shared__ __align__(16) ushort Ks[2][4096];
  __shared__ __align__(16) ushort Vs[2][4096];
  __shared__ __align__(16) ushort Ps[4][2][16][72];
  const int kvh = blockIdx.x;
  const int p = blockIdx.y;
  const int wave = threadIdx.x >> 6;
  const int lane = threadIdx.x & 63;
  const int col = lane & 15, quad = lane >> 4;
  const int h = kvh * 4 + wave;
  const ushort* qh = qbg + (size_t)h * S_LEN * HD;
  const ushort* kbase = kbg + (size_t)kvh * 32 * 4096;
  const ushort* vbase = vtg + (size_t)kvh * 32 * 4096;
  const int rsw = col & 7;

  auto stage = [&](int tile, int buf) {
#pragma unroll
    for (int g = 0; g < 2; ++g) {
      int gg = wave + g * 4;
      gld_lds16(kbase + (size_t)tile * 4096 + gg * 512 + lane * 8, &Ks[buf][gg * 512]);
      gld_lds16(vbase + (size_t)tile * 4096 + gg * 512 + lane * 8, &Vs[buf][gg * 512]);
    }
  };

  auto do_strip = [&](int s) {
    const int nt = (s >> 2) + 1;
    const int q0 = s * 16;
    bf16x8 qf[2];
    qf[0] = *(const bf16x8*)&qh[(size_t)(q0 + col) * HD + quad * 8];
    qf[1] = *(const bf16x8*)&qh[(size_t)(q0 + col) * HD + 32 + quad * 8];
    float l[4] = {};
    f32x4 o[4] = {};
    stage(0, 0);
    __syncthreads();
    for (int t = 0; t < nt; ++t) {
      const int buf = t & 1;
      if (t + 1 < nt) stage(t + 1, buf ^ 1);
      f32x4 sc[4] = {};
#pragma unroll
      for (int c = 0; c < 2; ++c) {
        const int chs = (c * 4 + quad) ^ rsw;
#pragma unroll
        for (int j = 0; j < 4; ++j) {
          bf16x8 kf = *(const bf16x8*)&Ks[buf][((j * 16 + col) * 8 + chs) * 8];
          sc[j] = __builtin_amdgcn_mfma_f32_16x16x32_bf16(qf[c], kf, sc[j], 0, 0, 0);
        }
      }
      const bool masked = (t == nt - 1);
#pragma unroll
      for (int r = 0; r < 4; ++r) {
        const int rowq = q0 + quad * 4 + r;
        float pr[4];
#pragma unroll
        for (int j = 0; j < 4; ++j) {
          float e = __builtin_amdgcn_exp2f(sc[j][r]);
          if (masked) e = (t * 64 + j * 16 + col > rowq) ? 0.f : e;
          pr[j] = e;
        }
        l[r] += (pr[0] + pr[1]) + (pr[2] + pr[3]);
        uint2 pk;
        pk.x = pack_bf2_rz(pr[0], pr[1]);
        pk.y = pack_bf2_rz(pr[2], pr[3]);
        *(uint2*)&Ps[wave][buf][quad * 4 + r][col * 4] = pk;
      }
#pragma unroll
      for (int c = 0; c < 2; ++c) {
        const int chs = (c * 4 + quad) ^ rsw;
        bf16x8 pf = *(const bf16x8*)&Ps[wave][buf][col][c * 32 + quad * 8];
#pragma unroll
        for (int db = 0; db < 4; ++db) {
          bf16x8 vf = *(const bf16x8*)&Vs[buf][((db * 16 + col) * 8 + chs) * 8];
          o[db] = __builtin_amdgcn_mfma_f32_16x16x32_bf16(pf, vf, o[db], 0, 0, 0);
        }
      }
      __syncthreads();
    }
#pragma unroll
    for (int r = 0; r < 4; ++r) {
      float ls = l[r];
      ls += __shfl_xor(ls, 1);
      ls += __shfl_xor(ls, 2);
      ls += __shfl_xor(ls, 4);
      ls += __shfl_xor(ls, 8);
      float inv = 1.0f / ls;
      int rowq = q0 + quad * 4 + r;
#pragma unroll
      for (int db = 0; db < 4; ++db)
        yb[(size_t)rowq * (NH * HD) + h * HD + db * 16 + col] = f2bf(o[db][r] * inv);
    }
  };

  do_strip(127 - p);
  do_strip(p);
}

extern "C" void kernel_launch(void* const* d_in, const int* in_sizes, int n_in,
                              void* d_out, int out_size, void* d_ws, size_t ws_size,
                              hipStream_t stream) {
  (void)in_sizes; (void)n_in; (void)out_size; (void)ws_size;
  const float* x  = (const float*)d_in[0];
  const float* fc = (const float*)d_in[1];
  const float* fs = (const float*)d_in[2];
  const float* wq = (const float*)d_in[4];
  const float* wk = (const float*)d_in[5];
  const float* wv = (const float*)d_in[6];
  const float* wo = (const float*)d_in[7];
  ushort* w = (ushort*)d_ws;
  const size_t M1 = 1024 * 1024;
  ushort* xb    = w;
  ushort* wqkvb = w + 4 * M1;
  ushort* wob   = w + 10 * M1;
  ushort* qkvb  = w + 14 * M1;
  ushort* qb    = w + 20 * M1;
  ushort* kb    = w + 24 * M1;
  ushort* vt    = w + 25 * M1;
  ushort* yb    = w + 26 * M1;

  convert_all<<<14336, 256, 0, stream>>>(x, wq, wk, wv, wo, xb, wqkvb, wob);
  gemm_bt<1, 192><<<dim3(QKVF / 192, S_LEN / 128), 256, 0, stream>>>(xb, wqkvb, qkvb, S_LEN, QKVF, DIMN);
  rope_layout<<<dim3(48, 8), 256, 0, stream>>>(qkvb, fc, fs, qb, kb, vt);
  attn<<<dim3(NKV, 64), 256, 0, stream>>>(qb, kb, vt, yb);
  gemm_bt<0, 128><<<dim3(DIMN / 128, S_LEN / 128), 256, 0, stream>>>(yb, wob, d_out, S_LEN, DIMN, NH * HD);
}

// Round 10
// 217.949 us; speedup vs baseline: 1.1173x; 1.1173x over previous
//
#include <hip/hip_runtime.h>

// Fused attention prefill, bf16 MFMA pipeline.
// ws layout (ushort units, 1M = 1024*1024):
//   xb 0..4M | wqkvb 4M..10M | wob 10M..14M | qkvb 14M..20M | qb 20M..24M
//   kb 24M..25M | vt 25M..26M | yb 26M..30M   => 60 MB total.
// kb/vt layout: [kvh][tile(32)][512 chunks][8 ushort]; chunk (r,ch) of the
// 64x64 tile lives at linear pos r*8 + (ch ^ (r&7))  (bank-swizzle).
// kb rows r = keys (natural); vt rows r = dims, columns = sigma-permuted key
// positions: pos p holds key u=(p&3)*16+(p>>2), matching attn's P store.

typedef __attribute__((ext_vector_type(8))) __bf16 bf16x8;
typedef __attribute__((ext_vector_type(4))) float f32x4;

#define S_LEN 2048
#define DIMN  2048
#define NH    32
#define NKV   8
#define HD    64
#define QKVF  3072

__device__ __forceinline__ ushort f2bf(float f) {
  union { float f; unsigned u; } v; v.f = f;
  unsigned r = v.u + 0x7fffu + ((v.u >> 16) & 1u);
  return (ushort)(r >> 16);
}
__device__ __forceinline__ unsigned pack_bf2_rz(float a, float b) {
  union { float f; unsigned u; } va, vb; va.f = a; vb.f = b;
  return (va.u >> 16) | (vb.u & 0xffff0000u);
}
__device__ __forceinline__ float bf2f(ushort u) {
  union { unsigned u; float f; } v; v.u = ((unsigned)u) << 16;
  return v.f;
}
__device__ __forceinline__ void gld_lds16(const void* g, void* l) {
  __builtin_amdgcn_global_load_lds(
      (const __attribute__((address_space(1))) unsigned int*)g,
      (__attribute__((address_space(3))) unsigned int*)l, 16, 0, 0);
}

// ---------------- f32 -> bf16 conversion (x, [wq;wk;wv], wo) ----------------
__global__ __launch_bounds__(256) void convert_all(
    const float* __restrict__ x, const float* __restrict__ wq,
    const float* __restrict__ wk, const float* __restrict__ wv,
    const float* __restrict__ wo, ushort* __restrict__ xb,
    ushort* __restrict__ wqkvb, ushort* __restrict__ wob) {
  const size_t NX = 4u * 1024 * 1024;
  const size_t NK = 1024 * 1024;
  size_t idx = ((size_t)blockIdx.x * 256 + threadIdx.x) * 4;
  const float* src; ushort* dst;
  if (idx < NX)                { src = x  + idx;                  dst = xb + idx; }
  else if (idx < 2 * NX)       { src = wq + (idx - NX);           dst = wqkvb + (idx - NX); }
  else if (idx < 2 * NX + NK)  { src = wk + (idx - 2 * NX);       dst = wqkvb + NX + (idx - 2 * NX); }
  else if (idx < 2 * NX + 2*NK){ src = wv + (idx - 2 * NX - NK);  dst = wqkvb + NX + NK + (idx - 2 * NX - NK); }
  else                         { src = wo + (idx - 2 * NX - 2*NK);dst = wob + (idx - 2 * NX - 2 * NK); }
  float4 v = *(const float4*)src;
  ushort4 o; o.x = f2bf(v.x); o.y = f2bf(v.y); o.z = f2bf(v.z); o.w = f2bf(v.w);
  *(ushort4*)dst = o;
}

// ---------------- GEMM: dbuf LDS + XOR bank swizzle, tile (BM x BN) ---------
// Balanced grids: pick BM,BN so grid == 512 blocks = exactly 2/CU (uniform
// per-CU work) with dbuf LDS < 64 KB (2-block residency; 80 KB in R9 dropped
// to 1 block/CU and regressed). qkv: 128x96 (56 KB). wo: 64x128 (48 KB).
// Chunk (row,ch) stored at physical ch^(row&7); staging permutes the GLOBAL
// source chunk per lane; fragment reads chunk=(c*4+quad)^(col&7) -> 0 confl.
template <int OUT_BF16, int BM, int BN>
__global__ __launch_bounds__(256) void gemm_bt(
    const ushort* __restrict__ A, const ushort* __restrict__ B,
    void* __restrict__ Cv, int M, int N, int K) {
  constexpr int IB = BM / 32;        // A 16-tiles per wave
  constexpr int JB = BN / 32;        // B 16-tiles per wave
  constexpr int NGA = BM / 8;        // A 8-row staging groups
  constexpr int GPW = (BM + BN) / 32;  // staging groups per wave
  __shared__ __align__(16) ushort As[2][BM * 64];
  __shared__ __align__(16) ushort Bs[2][BN * 64];
  const int n0 = blockIdx.x * BN, m0 = blockIdx.y * BM;
  const int t = threadIdx.x;
  const int lane = t & 63, wave = t >> 6;
  const int wm = (wave >> 1) * (BM / 2), wn = (wave & 1) * (BN / 2);
  const int col = lane & 15, quad = lane >> 4;
  const int sw = col & 7;
  const int lrow = lane >> 3;
  const int scol = ((lane & 7) ^ lrow) * 8;
  f32x4 acc[IB][JB] = {};

  auto stage = [&](int b, int kk) {
#pragma unroll
    for (int c = 0; c < GPW; ++c) {
      int g = wave * GPW + c;
      if (g < NGA)
        gld_lds16(&A[(size_t)(m0 + g * 8 + lrow) * K + kk + scol], &As[b][g * 8 * 64]);
      else
        gld_lds16(&B[(size_t)(n0 + (g - NGA) * 8 + lrow) * K + kk + scol],
                  &Bs[b][(g - NGA) * 8 * 64]);
    }
  };

  stage(0, 0);
  __syncthreads();
  for (int kk = 0; kk < K; kk += 64) {
    const int b = (kk >> 6) & 1;
    if (kk + 64 < K) stage(b ^ 1, kk + 64);
#pragma unroll
    for (int c = 0; c < 2; ++c) {
      const int chs = ((c * 4 + quad) ^ sw) * 8;
      bf16x8 af[IB], bfr[JB];
#pragma unroll
      for (int i = 0; i < IB; ++i)
        af[i] = *(const bf16x8*)&As[b][(wm + i * 16 + col) * 64 + chs];
#pragma unroll
      for (int j = 0; j < JB; ++j)
        bfr[j] = *(const bf16x8*)&Bs[b][(wn + j * 16 + col) * 64 + chs];
#pragma unroll
      for (int i = 0; i < IB; ++i)
#pragma unroll
        for (int j = 0; j < JB; ++j)
          acc[i][j] = __builtin_amdgcn_mfma_f32_16x16x32_bf16(af[i], bfr[j], acc[i][j], 0, 0, 0);
    }
    __syncthreads();
  }
#pragma unroll
  for (int i = 0; i < IB; ++i)
#pragma unroll
    for (int r = 0; r < 4; ++r) {
      int m = m0 + wm + i * 16 + quad * 4 + r;
      if (OUT_BF16) {
        ushort* C = (ushort*)Cv;
#pragma unroll
        for (int j = 0; j < JB; ++j)
          C[(size_t)m * N + n0 + wn + j * 16 + col] = f2bf(acc[i][j][r]);
      } else {
        float* C = (float*)Cv;
#pragma unroll
        for (int j = 0; j < JB; ++j)
          C[(size_t)m * N + n0 + wn + j * 16 + col] = acc[i][j][r];
      }
    }
}

// ---------------- RoPE + layout ---------------------------------------------
__global__ __launch_bounds__(256) void rope_layout(
    const ushort* __restrict__ qkv, const float* __restrict__ fc,
    const float* __restrict__ fs, ushort* __restrict__ qb,
    ushort* __restrict__ kb, ushort* __restrict__ vt) {
  __shared__ ushort T[64][72];
  const int hh = blockIdx.x;
  const int s0 = blockIdx.y * 256;
  const int t = threadIdx.x;
  if (hh < 32) {
    ushort* dst = qb + (size_t)hh * S_LEN * 64;
    const float qs = 0.18033688011112042f;  // (1/8)*log2(e)
    const int sr = t >> 4, dc = (t & 15) * 4, i0 = (t & 15) * 2;
#pragma unroll 4
    for (int pass = 0; pass < 16; ++pass) {
      int s = s0 + pass * 16 + sr;
      ushort4 vv = *(const ushort4*)&qkv[(size_t)s * QKVF + hh * 64 + dc];
      float2 cc = *(const float2*)&fc[s * 32 + i0];
      float2 ss = *(const float2*)&fs[s * 32 + i0];
      float xr0 = bf2f(vv.x), xi0 = bf2f(vv.y), xr1 = bf2f(vv.z), xi1 = bf2f(vv.w);
      ushort4 ov;
      ov.x = f2bf((xr0 * cc.x - xi0 * ss.x) * qs); ov.y = f2bf((xr0 * ss.x + xi0 * cc.x) * qs);
      ov.z = f2bf((xr1 * cc.y - xi1 * ss.y) * qs); ov.w = f2bf((xr1 * ss.y + xi1 * cc.y) * qs);
      *(ushort4*)&dst[(size_t)s * 64 + dc] = ov;
    }
  } else if (hh < 40) {
    const int kh2 = hh - 32;
    const int sr8 = t >> 3;
    const int ch = t & 7;
#pragma unroll 2
    for (int pass = 0; pass < 8; ++pass) {
      int s = s0 + pass * 32 + sr8;
      ushort in[8], out[8];
      *(int4*)&in[0] = *(const int4*)&qkv[(size_t)s * QKVF + 2048 + kh2 * 64 + ch * 8];
      float4 cc = *(const float4*)&fc[s * 32 + ch * 4];
      float4 ss4 = *(const float4*)&fs[s * 32 + ch * 4];
      const float* cp = &cc.x; const float* sp = &ss4.x;
#pragma unroll
      for (int i = 0; i < 4; ++i) {
        float xr = bf2f(in[2 * i]), xi = bf2f(in[2 * i + 1]);
        out[2 * i]     = f2bf(xr * cp[i] - xi * sp[i]);
        out[2 * i + 1] = f2bf(xr * sp[i] + xi * cp[i]);
      }
      int r = s & 63, tile = s >> 6;
      size_t pos = ((size_t)(kh2 * 32 + tile)) * 4096 + (r * 8 + (ch ^ (r & 7))) * 8;
      *(int4*)&kb[pos] = *(const int4*)&out[0];
    }
  } else {
    const int vh = hh - 40;
    for (int sub = 0; sub < 4; ++sub) {
      int sb = s0 + sub * 64;
      int sr = t >> 2, dc = (t & 3) * 16;
      ushort tmp[16];
      *(int4*)&tmp[0] = *(const int4*)&qkv[(size_t)(sb + sr) * QKVF + 2560 + vh * 64 + dc];
      *(int4*)&tmp[8] = *(const int4*)&qkv[(size_t)(sb + sr) * QKVF + 2560 + vh * 64 + dc + 8];
      __syncthreads();
      const int pcol = ((sr & 15) << 2) | (sr >> 4);  // sigma: key sr -> position
#pragma unroll
      for (int k = 0; k < 16; ++k) T[dc + k][pcol] = tmp[k];
      __syncthreads();
      int d = t >> 2;
      int ch0 = (t & 3) * 2, ch1 = ch0 + 1;
      int tile = sb >> 6;
      size_t base = ((size_t)(vh * 32 + tile)) * 4096;
      *(int4*)&vt[base + (d * 8 + (ch0 ^ (d & 7))) * 8] = *(const int4*)&T[d][ch0 * 8];
      *(int4*)&vt[base + (d * 8 + (ch1 ^ (d & 7))) * 8] = *(const int4*)&T[d][ch1 * 8];
    }
  }
}

// ---------------- Flash attention v7: LDS-shared KV, 4 GQA heads per block --
__global__ __launch_bounds__(256, 2) void attn(
    const ushort* __restrict__ qbg, const ushort* __restrict__ kbg,
    const ushort* __restrict__ vtg, ushort* __restrict__ yb) {
  __shared__ __align__(16) ushort Ks[2][4096];
  __shared__ __align__(16) ushort Vs[2][4096];
  __shared__ __align__(16) ushort Ps[4][2][16][72];
  const int kvh = blockIdx.x;
  const int p = blockIdx.y;
  const int wave = threadIdx.x >> 6;
  const int lane = threadIdx.x & 63;
  const int col = lane & 15, quad = lane >> 4;
  const int h = kvh * 4 + wave;
  const ushort* qh = qbg + (size_t)h * S_LEN * HD;
  const ushort* kbase = kbg + (size_t)kvh * 32 * 4096;
  const ushort* vbase = vtg + (size_t)kvh * 32 * 4096;
  const int rsw = col & 7;

  auto stage = [&](int tile, int buf) {
#pragma unroll
    for (int g = 0; g < 2; ++g) {
      int gg = wave + g * 4;
      gld_lds16(kbase + (size_t)tile * 4096 + gg * 512 + lane * 8, &Ks[buf][gg * 512]);
      gld_lds16(vbase + (size_t)tile * 4096 + gg * 512 + lane * 8, &Vs[buf][gg * 512]);
    }
  };

  auto do_strip = [&](int s) {
    const int nt = (s >> 2) + 1;
    const int q0 = s * 16;
    bf16x8 qf[2];
    qf[0] = *(const bf16x8*)&qh[(size_t)(q0 + col) * HD + quad * 8];
    qf[1] = *(const bf16x8*)&qh[(size_t)(q0 + col) * HD + 32 + quad * 8];
    float l[4] = {};
    f32x4 o[4] = {};
    stage(0, 0);
    __syncthreads();
    for (int t = 0; t < nt; ++t) {
      const int buf = t & 1;
      if (t + 1 < nt) stage(t + 1, buf ^ 1);
      f32x4 sc[4] = {};
#pragma unroll
      for (int c = 0; c < 2; ++c) {
        const int chs = (c * 4 + quad) ^ rsw;
#pragma unroll
        for (int j = 0; j < 4; ++j) {
          bf16x8 kf = *(const bf16x8*)&Ks[buf][((j * 16 + col) * 8 + chs) * 8];
          sc[j] = __builtin_amdgcn_mfma_f32_16x16x32_bf16(qf[c], kf, sc[j], 0, 0, 0);
        }
      }
      const bool masked = (t == nt - 1);
#pragma unroll
      for (int r = 0; r < 4; ++r) {
        const int rowq = q0 + quad * 4 + r;
        float pr[4];
#pragma unroll
        for (int j = 0; j < 4; ++j) {
          float e = __builtin_amdgcn_exp2f(sc[j][r]);
          if (masked) e = (t * 64 + j * 16 + col > rowq) ? 0.f : e;
          pr[j] = e;
        }
        l[r] += (pr[0] + pr[1]) + (pr[2] + pr[3]);
        uint2 pk;
        pk.x = pack_bf2_rz(pr[0], pr[1]);
        pk.y = pack_bf2_rz(pr[2], pr[3]);
        *(uint2*)&Ps[wave][buf][quad * 4 + r][col * 4] = pk;
      }
#pragma unroll
      for (int c = 0; c < 2; ++c) {
        const int chs = (c * 4 + quad) ^ rsw;
        bf16x8 pf = *(const bf16x8*)&Ps[wave][buf][col][c * 32 + quad * 8];
#pragma unroll
        for (int db = 0; db < 4; ++db) {
          bf16x8 vf = *(const bf16x8*)&Vs[buf][((db * 16 + col) * 8 + chs) * 8];
          o[db] = __builtin_amdgcn_mfma_f32_16x16x32_bf16(pf, vf, o[db], 0, 0, 0);
        }
      }
      __syncthreads();
    }
#pragma unroll
    for (int r = 0; r < 4; ++r) {
      float ls = l[r];
      ls += __shfl_xor(ls, 1);
      ls += __shfl_xor(ls, 2);
      ls += __shfl_xor(ls, 4);
      ls += __shfl_xor(ls, 8);
      float inv = 1.0f / ls;
      int rowq = q0 + quad * 4 + r;
#pragma unroll
      for (int db = 0; db < 4; ++db)
        yb[(size_t)rowq * (NH * HD) + h * HD + db * 16 + col] = f2bf(o[db][r] * inv);
    }
  };

  do_strip(127 - p);
  do_strip(p);
}

extern "C" void kernel_launch(void* const* d_in, const int* in_sizes, int n_in,
                              void* d_out, int out_size, void* d_ws, size_t ws_size,
                              hipStream_t stream) {
  (void)in_sizes; (void)n_in; (void)out_size; (void)ws_size;
  const float* x  = (const float*)d_in[0];
  const float* fc = (const float*)d_in[1];
  const float* fs = (const float*)d_in[2];
  const float* wq = (const float*)d_in[4];
  const float* wk = (const float*)d_in[5];
  const float* wv = (const float*)d_in[6];
  const float* wo = (const float*)d_in[7];
  ushort* w = (ushort*)d_ws;
  const size_t M1 = 1024 * 1024;
  ushort* xb    = w;
  ushort* wqkvb = w + 4 * M1;
  ushort* wob   = w + 10 * M1;
  ushort* qkvb  = w + 14 * M1;
  ushort* qb    = w + 20 * M1;
  ushort* kb    = w + 24 * M1;
  ushort* vt    = w + 25 * M1;
  ushort* yb    = w + 26 * M1;

  convert_all<<<14336, 256, 0, stream>>>(x, wq, wk, wv, wo, xb, wqkvb, wob);
  gemm_bt<1, 128, 96><<<dim3(QKVF / 96, S_LEN / 128), 256, 0, stream>>>(xb, wqkvb, qkvb, S_LEN, QKVF, DIMN);
  rope_layout<<<dim3(48, 8), 256, 0, stream>>>(qkvb, fc, fs, qb, kb, vt);
  attn<<<dim3(NKV, 64), 256, 0, stream>>>(qb, kb, vt, yb);
  gemm_bt<0, 64, 128><<<dim3(DIMN / 128, S_LEN / 64), 256, 0, stream>>>(yb, wob, d_out, S_LEN, DIMN, NH * HD);
}

// Round 11
// 216.369 us; speedup vs baseline: 1.1254x; 1.0073x over previous
//
#include <hip/hip_runtime.h>

// Fused attention prefill, bf16 MFMA pipeline.
// ws layout (ushort units, 1M = 1024*1024):
//   xb 0..4M | wqkvb 4M..10M | wob 10M..14M | qkvb 14M..20M | qb 20M..24M
//   kb 24M..25M | vt 25M..26M | yb 26M..30M   => 60 MB total.
// kb/vt layout: [kvh][tile(32)][512 chunks][8 ushort]; chunk (r,ch) of the
// 64x64 tile lives at linear pos r*8 + (ch ^ (r&7))  (bank-swizzle).
// kb rows r = keys (natural); vt rows r = dims, columns = sigma-permuted key
// positions: pos p holds key u=(p&3)*16+(p>>2), matching attn's P store.

typedef __attribute__((ext_vector_type(8))) __bf16 bf16x8;
typedef __attribute__((ext_vector_type(4))) float f32x4;

#define S_LEN 2048
#define DIMN  2048
#define NH    32
#define NKV   8
#define HD    64
#define QKVF  3072

__device__ __forceinline__ ushort f2bf(float f) {
  union { float f; unsigned u; } v; v.f = f;
  unsigned r = v.u + 0x7fffu + ((v.u >> 16) & 1u);
  return (ushort)(r >> 16);
}
__device__ __forceinline__ unsigned pack_bf2_rz(float a, float b) {
  union { float f; unsigned u; } va, vb; va.f = a; vb.f = b;
  return (va.u >> 16) | (vb.u & 0xffff0000u);
}
__device__ __forceinline__ float bf2f(ushort u) {
  union { unsigned u; float f; } v; v.u = ((unsigned)u) << 16;
  return v.f;
}
__device__ __forceinline__ void gld_lds16(const void* g, void* l) {
  __builtin_amdgcn_global_load_lds(
      (const __attribute__((address_space(1))) unsigned int*)g,
      (__attribute__((address_space(3))) unsigned int*)l, 16, 0, 0);
}

// ---------------- f32 -> bf16 conversion (x, [wq;wk;wv], wo) ----------------
__global__ __launch_bounds__(256) void convert_all(
    const float* __restrict__ x, const float* __restrict__ wq,
    const float* __restrict__ wk, const float* __restrict__ wv,
    const float* __restrict__ wo, ushort* __restrict__ xb,
    ushort* __restrict__ wqkvb, ushort* __restrict__ wob) {
  const size_t NX = 4u * 1024 * 1024;
  const size_t NK = 1024 * 1024;
  size_t idx = ((size_t)blockIdx.x * 256 + threadIdx.x) * 4;
  const float* src; ushort* dst;
  if (idx < NX)                { src = x  + idx;                  dst = xb + idx; }
  else if (idx < 2 * NX)       { src = wq + (idx - NX);           dst = wqkvb + (idx - NX); }
  else if (idx < 2 * NX + NK)  { src = wk + (idx - 2 * NX);       dst = wqkvb + NX + (idx - 2 * NX); }
  else if (idx < 2 * NX + 2*NK){ src = wv + (idx - 2 * NX - NK);  dst = wqkvb + NX + NK + (idx - 2 * NX - NK); }
  else                         { src = wo + (idx - 2 * NX - 2*NK);dst = wob + (idx - 2 * NX - 2 * NK); }
  float4 v = *(const float4*)src;
  ushort4 o; o.x = f2bf(v.x); o.y = f2bf(v.y); o.z = f2bf(v.z); o.w = f2bf(v.w);
  *(ushort4*)dst = o;
}

// ---------------- GEMM: dbuf LDS + XOR bank swizzle, tile (BM x BN) ---------
// Balanced grids: 512 blocks = exactly 2/CU, dbuf LDS < 64 KB (2-block
// residency). qkv: 128x96 (56 KB). wo: 64x128 (48 KB).
template <int OUT_BF16, int BM, int BN>
__global__ __launch_bounds__(256) void gemm_bt(
    const ushort* __restrict__ A, const ushort* __restrict__ B,
    void* __restrict__ Cv, int M, int N, int K) {
  constexpr int IB = BM / 32;
  constexpr int JB = BN / 32;
  constexpr int NGA = BM / 8;
  constexpr int GPW = (BM + BN) / 32;
  __shared__ __align__(16) ushort As[2][BM * 64];
  __shared__ __align__(16) ushort Bs[2][BN * 64];
  const int n0 = blockIdx.x * BN, m0 = blockIdx.y * BM;
  const int t = threadIdx.x;
  const int lane = t & 63, wave = t >> 6;
  const int wm = (wave >> 1) * (BM / 2), wn = (wave & 1) * (BN / 2);
  const int col = lane & 15, quad = lane >> 4;
  const int sw = col & 7;
  const int lrow = lane >> 3;
  const int scol = ((lane & 7) ^ lrow) * 8;
  f32x4 acc[IB][JB] = {};

  auto stage = [&](int b, int kk) {
#pragma unroll
    for (int c = 0; c < GPW; ++c) {
      int g = wave * GPW + c;
      if (g < NGA)
        gld_lds16(&A[(size_t)(m0 + g * 8 + lrow) * K + kk + scol], &As[b][g * 8 * 64]);
      else
        gld_lds16(&B[(size_t)(n0 + (g - NGA) * 8 + lrow) * K + kk + scol],
                  &Bs[b][(g - NGA) * 8 * 64]);
    }
  };

  stage(0, 0);
  __syncthreads();
  for (int kk = 0; kk < K; kk += 64) {
    const int b = (kk >> 6) & 1;
    if (kk + 64 < K) stage(b ^ 1, kk + 64);
#pragma unroll
    for (int c = 0; c < 2; ++c) {
      const int chs = ((c * 4 + quad) ^ sw) * 8;
      bf16x8 af[IB], bfr[JB];
#pragma unroll
      for (int i = 0; i < IB; ++i)
        af[i] = *(const bf16x8*)&As[b][(wm + i * 16 + col) * 64 + chs];
#pragma unroll
      for (int j = 0; j < JB; ++j)
        bfr[j] = *(const bf16x8*)&Bs[b][(wn + j * 16 + col) * 64 + chs];
#pragma unroll
      for (int i = 0; i < IB; ++i)
#pragma unroll
        for (int j = 0; j < JB; ++j)
          acc[i][j] = __builtin_amdgcn_mfma_f32_16x16x32_bf16(af[i], bfr[j], acc[i][j], 0, 0, 0);
    }
    __syncthreads();
  }
#pragma unroll
  for (int i = 0; i < IB; ++i)
#pragma unroll
    for (int r = 0; r < 4; ++r) {
      int m = m0 + wm + i * 16 + quad * 4 + r;
      if (OUT_BF16) {
        ushort* C = (ushort*)Cv;
#pragma unroll
        for (int j = 0; j < JB; ++j)
          C[(size_t)m * N + n0 + wn + j * 16 + col] = f2bf(acc[i][j][r]);
      } else {
        float* C = (float*)Cv;
#pragma unroll
        for (int j = 0; j < JB; ++j)
          C[(size_t)m * N + n0 + wn + j * 16 + col] = acc[i][j][r];
      }
    }
}

// ---------------- RoPE + layout ---------------------------------------------
__global__ __launch_bounds__(256) void rope_layout(
    const ushort* __restrict__ qkv, const float* __restrict__ fc,
    const float* __restrict__ fs, ushort* __restrict__ qb,
    ushort* __restrict__ kb, ushort* __restrict__ vt) {
  __shared__ ushort T[64][72];
  const int hh = blockIdx.x;
  const int s0 = blockIdx.y * 256;
  const int t = threadIdx.x;
  if (hh < 32) {
    ushort* dst = qb + (size_t)hh * S_LEN * 64;
    const float qs = 0.18033688011112042f;  // (1/8)*log2(e)
    const int sr = t >> 4, dc = (t & 15) * 4, i0 = (t & 15) * 2;
#pragma unroll 4
    for (int pass = 0; pass < 16; ++pass) {
      int s = s0 + pass * 16 + sr;
      ushort4 vv = *(const ushort4*)&qkv[(size_t)s * QKVF + hh * 64 + dc];
      float2 cc = *(const float2*)&fc[s * 32 + i0];
      float2 ss = *(const float2*)&fs[s * 32 + i0];
      float xr0 = bf2f(vv.x), xi0 = bf2f(vv.y), xr1 = bf2f(vv.z), xi1 = bf2f(vv.w);
      ushort4 ov;
      ov.x = f2bf((xr0 * cc.x - xi0 * ss.x) * qs); ov.y = f2bf((xr0 * ss.x + xi0 * cc.x) * qs);
      ov.z = f2bf((xr1 * cc.y - xi1 * ss.y) * qs); ov.w = f2bf((xr1 * ss.y + xi1 * cc.y) * qs);
      *(ushort4*)&dst[(size_t)s * 64 + dc] = ov;
    }
  } else if (hh < 40) {
    const int kh2 = hh - 32;
    const int sr8 = t >> 3;
    const int ch = t & 7;
#pragma unroll 2
    for (int pass = 0; pass < 8; ++pass) {
      int s = s0 + pass * 32 + sr8;
      ushort in[8], out[8];
      *(int4*)&in[0] = *(const int4*)&qkv[(size_t)s * QKVF + 2048 + kh2 * 64 + ch * 8];
      float4 cc = *(const float4*)&fc[s * 32 + ch * 4];
      float4 ss4 = *(const float4*)&fs[s * 32 + ch * 4];
      const float* cp = &cc.x; const float* sp = &ss4.x;
#pragma unroll
      for (int i = 0; i < 4; ++i) {
        float xr = bf2f(in[2 * i]), xi = bf2f(in[2 * i + 1]);
        out[2 * i]     = f2bf(xr * cp[i] - xi * sp[i]);
        out[2 * i + 1] = f2bf(xr * sp[i] + xi * cp[i]);
      }
      int r = s & 63, tile = s >> 6;
      size_t pos = ((size_t)(kh2 * 32 + tile)) * 4096 + (r * 8 + (ch ^ (r & 7))) * 8;
      *(int4*)&kb[pos] = *(const int4*)&out[0];
    }
  } else {
    const int vh = hh - 40;
    for (int sub = 0; sub < 4; ++sub) {
      int sb = s0 + sub * 64;
      int sr = t >> 2, dc = (t & 3) * 16;
      ushort tmp[16];
      *(int4*)&tmp[0] = *(const int4*)&qkv[(size_t)(sb + sr) * QKVF + 2560 + vh * 64 + dc];
      *(int4*)&tmp[8] = *(const int4*)&qkv[(size_t)(sb + sr) * QKVF + 2560 + vh * 64 + dc + 8];
      __syncthreads();
      const int pcol = ((sr & 15) << 2) | (sr >> 4);  // sigma: key sr -> position
#pragma unroll
      for (int k = 0; k < 16; ++k) T[dc + k][pcol] = tmp[k];
      __syncthreads();
      int d = t >> 2;
      int ch0 = (t & 3) * 2, ch1 = ch0 + 1;
      int tile = sb >> 6;
      size_t base = ((size_t)(vh * 32 + tile)) * 4096;
      *(int4*)&vt[base + (d * 8 + (ch0 ^ (d & 7))) * 8] = *(const int4*)&T[d][ch0 * 8];
      *(int4*)&vt[base + (d * 8 + (ch1 ^ (d & 7))) * 8] = *(const int4*)&T[d][ch1 * 8];
    }
  }
}

// ---------------- Flash attention v8: 1 strip/block, 4 blocks/CU ------------
// Grid (8 kvh, 128 strips) = 1024 blocks = 4/CU, ALL co-resident: 4
// independent barrier streams per CU cover each other's vmcnt(0) drains
// (R10 had only 2). LDS cut to exactly 40960 B: Ks 16K + Vs 16K + Ps 8K
// (parity dropped - within-wave DS ordering makes the PV-read ->
// next-tile-P-write WAR safe; Ps unpadded with XOR chunk swizzle).
__global__ __launch_bounds__(256, 2) void attn(
    const ushort* __restrict__ qbg, const ushort* __restrict__ kbg,
    const ushort* __restrict__ vtg, ushort* __restrict__ yb) {
  __shared__ __align__(16) ushort Ks[2][4096];
  __shared__ __align__(16) ushort Vs[2][4096];
  __shared__ __align__(16) ushort Ps[4][16][64];  // [wave][row][XOR-swizzled]
  const int kvh = blockIdx.x;
  const int s = blockIdx.y;            // 16-row Q strip
  const int wave = threadIdx.x >> 6;
  const int lane = threadIdx.x & 63;
  const int col = lane & 15, quad = lane >> 4;
  const int h = kvh * 4 + wave;
  const ushort* qh = qbg + (size_t)h * S_LEN * HD;
  const ushort* kbase = kbg + (size_t)kvh * 32 * 4096;
  const ushort* vbase = vtg + (size_t)kvh * 32 * 4096;
  const int rsw = col & 7;

  auto stage = [&](int tile, int buf) {
#pragma unroll
    for (int g = 0; g < 2; ++g) {
      int gg = wave + g * 4;
      gld_lds16(kbase + (size_t)tile * 4096 + gg * 512 + lane * 8, &Ks[buf][gg * 512]);
      gld_lds16(vbase + (size_t)tile * 4096 + gg * 512 + lane * 8, &Vs[buf][gg * 512]);
    }
  };

  const int nt = (s >> 2) + 1;
  const int q0 = s * 16;
  bf16x8 qf[2];
  qf[0] = *(const bf16x8*)&qh[(size_t)(q0 + col) * HD + quad * 8];
  qf[1] = *(const bf16x8*)&qh[(size_t)(q0 + col) * HD + 32 + quad * 8];
  float l[4] = {};
  f32x4 o[4] = {};
  stage(0, 0);
  __syncthreads();
  for (int t = 0; t < nt; ++t) {
    const int buf = t & 1;
    if (t + 1 < nt) stage(t + 1, buf ^ 1);
    f32x4 sc[4] = {};
#pragma unroll
    for (int c = 0; c < 2; ++c) {
      const int chs = (c * 4 + quad) ^ rsw;
#pragma unroll
      for (int j = 0; j < 4; ++j) {
        bf16x8 kf = *(const bf16x8*)&Ks[buf][((j * 16 + col) * 8 + chs) * 8];
        sc[j] = __builtin_amdgcn_mfma_f32_16x16x32_bf16(qf[c], kf, sc[j], 0, 0, 0);
      }
    }
    const bool masked = (t == nt - 1);
#pragma unroll
    for (int r = 0; r < 4; ++r) {
      const int rowq = q0 + quad * 4 + r;
      float pr[4];
#pragma unroll
      for (int j = 0; j < 4; ++j) {
        float e = __builtin_amdgcn_exp2f(sc[j][r]);
        if (masked) e = (t * 64 + j * 16 + col > rowq) ? 0.f : e;
        pr[j] = e;
      }
      l[r] += (pr[0] + pr[1]) + (pr[2] + pr[3]);
      uint2 pk;
      pk.x = pack_bf2_rz(pr[0], pr[1]);
      pk.y = pack_bf2_rz(pr[2], pr[3]);
      const int prow = quad * 4 + r;
      *(uint2*)&Ps[wave][prow][(((col >> 1) ^ (prow & 7)) << 3) + ((col & 1) << 2)] = pk;
    }
#pragma unroll
    for (int c = 0; c < 2; ++c) {
      const int chs = (c * 4 + quad) ^ rsw;
      bf16x8 pf = *(const bf16x8*)&Ps[wave][col][((c * 4 + quad) ^ (col & 7)) * 8];
#pragma unroll
      for (int db = 0; db < 4; ++db) {
        bf16x8 vf = *(const bf16x8*)&Vs[buf][((db * 16 + col) * 8 + chs) * 8];
        o[db] = __builtin_amdgcn_mfma_f32_16x16x32_bf16(pf, vf, o[db], 0, 0, 0);
      }
    }
    __syncthreads();
  }
#pragma unroll
  for (int r = 0; r < 4; ++r) {
    float ls = l[r];
    ls += __shfl_xor(ls, 1);
    ls += __shfl_xor(ls, 2);
    ls += __shfl_xor(ls, 4);
    ls += __shfl_xor(ls, 8);
    float inv = 1.0f / ls;
    int rowq = q0 + quad * 4 + r;
#pragma unroll
    for (int db = 0; db < 4; ++db)
      yb[(size_t)rowq * (NH * HD) + h * HD + db * 16 + col] = f2bf(o[db][r] * inv);
  }
}

extern "C" void kernel_launch(void* const* d_in, const int* in_sizes, int n_in,
                              void* d_out, int out_size, void* d_ws, size_t ws_size,
                              hipStream_t stream) {
  (void)in_sizes; (void)n_in; (void)out_size; (void)ws_size;
  const float* x  = (const float*)d_in[0];
  const float* fc = (const float*)d_in[1];
  const float* fs = (const float*)d_in[2];
  const float* wq = (const float*)d_in[4];
  const float* wk = (const float*)d_in[5];
  const float* wv = (const float*)d_in[6];
  const float* wo = (const float*)d_in[7];
  ushort* w = (ushort*)d_ws;
  const size_t M1 = 1024 * 1024;
  ushort* xb    = w;
  ushort* wqkvb = w + 4 * M1;
  ushort* wob   = w + 10 * M1;
  ushort* qkvb  = w + 14 * M1;
  ushort* qb    = w + 20 * M1;
  ushort* kb    = w + 24 * M1;
  ushort* vt    = w + 25 * M1;
  ushort* yb    = w + 26 * M1;

  convert_all<<<14336, 256, 0, stream>>>(x, wq, wk, wv, wo, xb, wqkvb, wob);
  gemm_bt<1, 128, 96><<<dim3(QKVF / 96, S_LEN / 128), 256, 0, stream>>>(xb, wqkvb, qkvb, S_LEN, QKVF, DIMN);
  rope_layout<<<dim3(48, 8), 256, 0, stream>>>(qkvb, fc, fs, qb, kb, vt);
  attn<<<dim3(NKV, 128), 256, 0, stream>>>(qb, kb, vt, yb);
  gemm_bt<0, 64, 128><<<dim3(DIMN / 128, S_LEN / 64), 256, 0, stream>>>(yb, wob, d_out, S_LEN, DIMN, NH * HD);
}